// Round 6
// baseline (2461.857 us; speedup 1.0000x reference)
//
#include <hip/hip_runtime.h>

// d_out layout: gcn_users [U][192] then gcn_items [I][192]
//   cols 0:64 = emb, 64:128 = gcn1, 128:192 = gcn2
//
// Bucket-level pipeline (no row-sorted CSR):
//   1. hist: per-bucket edge counts (bucket = 64 rows, both sides combined)
//   2. scan: exclusive scan of bucket counts -> rp (persistent) + gwp (working)
//   3. bin:  tiled two-phase reservation binning -> scv[2E] packed runs
//            entry = ( (row6<<24)|col24 , val_f32 )
//   4. gather_bucket<STAGE>: one WG per bucket, LDS acc[64][64] f32,
//      ds_add_f32 accumulate, coalesced epilogue (+residual, +emb copy).

#define TILE    4096
#define MAX_NB  4096

// ---------------- 1. bucket histogram ----------------
__global__ __launch_bounds__(256) void hist_kernel(
    const int* __restrict__ eu, const int* __restrict__ ei,
    int* __restrict__ bcnt, int E, int nb_u, int nb)
{
    __shared__ int cnt[MAX_NB];
    int t0 = blockIdx.x * TILE;
    int n  = min(TILE, E - t0);
    for (int b = threadIdx.x; b < nb; b += 256) cnt[b] = 0;
    __syncthreads();
    for (int k = threadIdx.x; k < n; k += 256) {
        atomicAdd(&cnt[eu[t0 + k] >> 6], 1);
        atomicAdd(&cnt[nb_u + (ei[t0 + k] >> 6)], 1);
    }
    __syncthreads();
    for (int b = threadIdx.x; b < nb; b += 256)
        if (cnt[b]) atomicAdd(&bcnt[b], cnt[b]);
}

// ---------------- 2. single-WG exclusive scan (n <= 4096) ----------------
__global__ __launch_bounds__(1024) void scan_kernel(
    const int* __restrict__ bcnt, int* __restrict__ rp, int* __restrict__ gwp, int nb)
{
    __shared__ int part[1024];
    int t  = threadIdx.x;
    int i0 = t * 4;
    int x0 = (i0 + 0 < nb) ? bcnt[i0 + 0] : 0;
    int x1 = (i0 + 1 < nb) ? bcnt[i0 + 1] : 0;
    int x2 = (i0 + 2 < nb) ? bcnt[i0 + 2] : 0;
    int x3 = (i0 + 3 < nb) ? bcnt[i0 + 3] : 0;
    int s = x0 + x1 + x2 + x3;
    part[t] = s;
    __syncthreads();
    #pragma unroll
    for (int off = 1; off < 1024; off <<= 1) {
        int v = (t >= off) ? part[t - off] : 0;
        __syncthreads();
        part[t] += v;
        __syncthreads();
    }
    int p = part[t] - s;  // exclusive base for this thread's 4 elements
    if (i0 + 0 < nb) { rp[i0 + 0] = p; gwp[i0 + 0] = p; p += x0; }
    if (i0 + 1 < nb) { rp[i0 + 1] = p; gwp[i0 + 1] = p; p += x1; }
    if (i0 + 2 < nb) { rp[i0 + 2] = p; gwp[i0 + 2] = p; p += x2; }
    if (i0 + 3 < nb) { rp[i0 + 3] = p; gwp[i0 + 3] = p; p += x3; }
    if (t == 1023) rp[nb] = part[1023];
}

// ---------------- 3. tiled reservation binning ----------------
__global__ __launch_bounds__(256) void bin_kernel(
    const int* __restrict__ eu, const int* __restrict__ ei,
    const float* __restrict__ uiv, const float* __restrict__ iuv,
    int* __restrict__ gwp, int2* __restrict__ scv,
    int E, int nb_u, int nb)
{
    __shared__ int cnt[MAX_NB];
    __shared__ int base[MAX_NB];
    int t0 = blockIdx.x * TILE;
    int n  = min(TILE, E - t0);
    for (int b = threadIdx.x; b < nb; b += 256) cnt[b] = 0;
    __syncthreads();
    for (int k = threadIdx.x; k < n; k += 256) {
        atomicAdd(&cnt[eu[t0 + k] >> 6], 1);
        atomicAdd(&cnt[nb_u + (ei[t0 + k] >> 6)], 1);
    }
    __syncthreads();
    for (int b = threadIdx.x; b < nb; b += 256) {
        int c = cnt[b];
        base[b] = c ? atomicAdd(&gwp[b], c) : 0;
        cnt[b] = 0;
    }
    __syncthreads();
    for (int k = threadIdx.x; k < n; k += 256) {
        int u = eu[t0 + k], it = ei[t0 + k];
        int bu = u >> 6;
        int pu = base[bu] + atomicAdd(&cnt[bu], 1);
        scv[pu] = make_int2(((u & 63) << 24) | it, __float_as_int(uiv[t0 + k]));
        int bi = nb_u + (it >> 6);
        int pi = base[bi] + atomicAdd(&cnt[bi], 1);
        scv[pi] = make_int2(((it & 63) << 24) | u, __float_as_int(iuv[t0 + k]));
    }
}

// ---------------- 4. bucket gather: LDS-accumulating SpMM ----------------
template <int STAGE>
__global__ __launch_bounds__(256) void gather_bucket(
    const int* __restrict__ rp, const int2* __restrict__ scv,
    const float* __restrict__ emb_u, const float* __restrict__ emb_i,
    float* __restrict__ out_u, float* __restrict__ out_i,
    int U, int I, int nb_u)
{
    __shared__ float acc[64 * 64];
    int b = blockIdx.x;
    bool uside = (b < nb_u);
    int row0  = (uside ? b : b - nb_u) << 6;
    int nrows = (uside ? U : I) - row0;
    if (nrows > 64) nrows = 64;
    int beg = rp[b], end = rp[b + 1];
    int f = threadIdx.x & 63, w = threadIdx.x >> 6;

    for (int t = threadIdx.x; t < 64 * 64; t += 256) acc[t] = 0.f;
    __syncthreads();

    const float* src; int ss;
    if (STAGE == 1) { src = uside ? emb_i : emb_u;                ss = 64;  }
    else            { src = (uside ? out_i : out_u) + 64;         ss = 192; }

    // each wave owns edges k = beg+w, beg+w+4, ... ; unroll 2 for MLP
    int k = beg + w;
    for (; k + 4 < end; k += 8) {
        int2 ca = scv[k], cb = scv[k + 4];
        float xa = src[(ca.x & 0xFFFFFF) * ss + f];
        float xb = src[(cb.x & 0xFFFFFF) * ss + f];
        atomicAdd(&acc[(((unsigned)ca.x >> 24) << 6) | f], __int_as_float(ca.y) * xa);
        atomicAdd(&acc[(((unsigned)cb.x >> 24) << 6) | f], __int_as_float(cb.y) * xb);
    }
    for (; k < end; k += 4) {
        int2 c = scv[k];
        float x = src[(c.x & 0xFFFFFF) * ss + f];
        atomicAdd(&acc[(((unsigned)c.x >> 24) << 6) | f], __int_as_float(c.y) * x);
    }
    __syncthreads();

    float* outp       = uside ? out_u : out_i;
    const float* embp = uside ? emb_u : emb_i;
    for (int r = w; r < nrows; r += 4) {
        int grow = row0 + r;
        float res;
        if (STAGE == 1) res = embp[grow * 64 + f];
        else            res = outp[grow * 192 + 64 + f];
        outp[grow * 192 + (STAGE == 1 ? 64 : 128) + f] = acc[(r << 6) | f] + res;
        if (STAGE == 1) outp[grow * 192 + f] = res;   // emb copy to col 0
    }
}

extern "C" void kernel_launch(void* const* d_in, const int* in_sizes, int n_in,
                              void* d_out, int out_size, void* d_ws, size_t ws_size,
                              hipStream_t stream)
{
    const float* emb_u   = (const float*)d_in[0];
    const float* emb_i   = (const float*)d_in[1];
    const float* ui_vals = (const float*)d_in[2];
    const float* iu_vals = (const float*)d_in[3];
    const int*   e_user  = (const int*)d_in[4];
    const int*   e_item  = (const int*)d_in[5];

    const int F = 64;
    const int U = in_sizes[0] / F;
    const int I = in_sizes[1] / F;
    const int E = in_sizes[4];

    float* out_u = (float*)d_out;            // [U][192]
    float* out_i = out_u + (size_t)U * 192;  // [I][192]

    int nb_u = (U + 63) >> 6;
    int nb_i = (I + 63) >> 6;
    int nb   = nb_u + nb_i;
    if (nb > MAX_NB) return;                 // not expected for this problem

    // ---- workspace layout ----
    char* base = (char*)d_ws;
    size_t off = 0;
    auto alloc = [&](size_t bytes, size_t align) -> char* {
        off = (off + align - 1) & ~(align - 1);
        char* p = base + off;
        off += bytes;
        return p;
    };
    int*  bcnt = (int*)alloc((size_t)nb * 4, 4);
    int*  rp   = (int*)alloc((size_t)(nb + 1) * 4, 4);
    int*  gwp  = (int*)alloc((size_t)nb * 4, 4);
    int2* scv  = (int2*)alloc((size_t)2 * E * 8, 8);
    if (ws_size < off) return;               // not expected on this harness

    int ntiles = (E + TILE - 1) / TILE;

    hipMemsetAsync(bcnt, 0, (size_t)nb * 4, stream);
    hist_kernel<<<ntiles, 256, 0, stream>>>(e_user, e_item, bcnt, E, nb_u, nb);
    scan_kernel<<<1, 1024, 0, stream>>>(bcnt, rp, gwp, nb);
    bin_kernel<<<ntiles, 256, 0, stream>>>(e_user, e_item, ui_vals, iu_vals,
                                           gwp, scv, E, nb_u, nb);

    gather_bucket<1><<<nb, 256, 0, stream>>>(rp, scv, emb_u, emb_i,
                                             out_u, out_i, U, I, nb_u);
    gather_bucket<2><<<nb, 256, 0, stream>>>(rp, scv, emb_u, emb_i,
                                             out_u, out_i, U, I, nb_u);
}

// Round 7
// 516.070 us; speedup vs baseline: 4.7704x; 4.7704x over previous
//
#include <hip/hip_runtime.h>

// d_out layout: gcn_users [U][192] then gcn_items [I][192]
//   cols 0:64 = emb, 64:128 = gcn1, 128:192 = gcn2
//
// Round-5 pipeline (row-level CSR via tiled reservation binning + per-bucket
// place; gather SpMM one-wave-per-row) with BF16 GATHER SOURCES:
//   - emb converted to bf16 (overlaying dead scv staging) for stage-1 gathers
//   - stage-1 epilogue emits dense bf16 gcn1; stage-2 gathers read it
//   - residuals/outputs stay f32.

typedef unsigned long long ull;

__device__ inline ushort f2bf(float x) {            // RNE f32 -> bf16
    unsigned u = __float_as_uint(x);
    return (ushort)((u + 0x7FFF + ((u >> 16) & 1)) >> 16);
}

// ---------------- CSR build ----------------

__global__ void count_kernel(const int* __restrict__ eu, const int* __restrict__ ei,
                             int* __restrict__ du, int* __restrict__ di, int E)
{
    int e = blockIdx.x * blockDim.x + threadIdx.x;
    if (e >= E) return;
    atomicAdd(&du[eu[e]], 1);
    atomicAdd(&di[ei[e]], 1);
}

__global__ void scan_block_kernel(const int* __restrict__ in, int n,
                                  int* __restrict__ out, int* __restrict__ bsums)
{
    __shared__ int tmp[1024];
    int idx = blockIdx.x * 1024 + threadIdx.x;
    int x = (idx < n) ? in[idx] : 0;
    tmp[threadIdx.x] = x;
    __syncthreads();
    #pragma unroll
    for (int off = 1; off < 1024; off <<= 1) {
        int t = (threadIdx.x >= off) ? tmp[threadIdx.x - off] : 0;
        __syncthreads();
        tmp[threadIdx.x] += t;
        __syncthreads();
    }
    if (idx < n) out[idx] = tmp[threadIdx.x] - x;
    if (threadIdx.x == 1023 && bsums) bsums[blockIdx.x] = tmp[1023];
}

__global__ void scan_fixup_kernel(int* __restrict__ rp, int* __restrict__ wp,
                                  const int* __restrict__ bscan, int n, int total)
{
    int idx = blockIdx.x * blockDim.x + threadIdx.x;
    if (idx < n) {
        int v = rp[idx] + bscan[idx >> 10];
        rp[idx] = v;
        if (wp) wp[idx] = v;
    } else if (idx == n) {
        rp[n] = total;
    }
}

__global__ void bwp_init_kernel(const int* __restrict__ rp_u, const int* __restrict__ rp_i,
                                int* __restrict__ gwp_u, int* __restrict__ gwp_i,
                                int nb_u, int nb_i, int U, int I)
{
    int idx = blockIdx.x * blockDim.x + threadIdx.x;
    if (idx < nb_u) gwp_u[idx] = rp_u[min(idx << 7, U)];
    if (idx < nb_i) gwp_i[idx] = rp_i[min(idx << 6, I)];
}

#define TILE 8192
__global__ __launch_bounds__(256) void bin2_kernel(
    const int* __restrict__ eu, const int* __restrict__ ei,
    const float* __restrict__ uiv, const float* __restrict__ iuv,
    int* __restrict__ gwp_u, int* __restrict__ gwp_i,
    ull* __restrict__ scv_u, ull* __restrict__ scv_i,
    int E, int nb_u, int nb_i)
{
    __shared__ int cnt[1024];
    __shared__ int base[1024];
    int tile0 = blockIdx.x * TILE;
    int n = min(TILE, E - tile0);

    for (int b = threadIdx.x; b < nb_u; b += 256) cnt[b] = 0;
    __syncthreads();
    for (int k = threadIdx.x; k < n; k += 256)
        atomicAdd(&cnt[eu[tile0 + k] >> 7], 1);
    __syncthreads();
    for (int b = threadIdx.x; b < nb_u; b += 256) {
        int c = cnt[b];
        base[b] = c ? atomicAdd(&gwp_u[b], c) : 0;
        cnt[b] = 0;
    }
    __syncthreads();
    for (int k = threadIdx.x; k < n; k += 256) {
        int u  = eu[tile0 + k];
        int it = ei[tile0 + k];
        float v = uiv[tile0 + k];
        int b = u >> 7;
        int pos = base[b] + atomicAdd(&cnt[b], 1);
        scv_u[pos] = ((ull)__float_as_uint(v) << 32) |
                     ((ull)(u & 127) << 24) | (unsigned)it;
    }
    __syncthreads();

    for (int b = threadIdx.x; b < nb_i; b += 256) cnt[b] = 0;
    __syncthreads();
    for (int k = threadIdx.x; k < n; k += 256)
        atomicAdd(&cnt[ei[tile0 + k] >> 6], 1);
    __syncthreads();
    for (int b = threadIdx.x; b < nb_i; b += 256) {
        int c = cnt[b];
        base[b] = c ? atomicAdd(&gwp_i[b], c) : 0;
        cnt[b] = 0;
    }
    __syncthreads();
    for (int k = threadIdx.x; k < n; k += 256) {
        int it = ei[tile0 + k];
        int u  = eu[tile0 + k];
        float v = iuv[tile0 + k];
        int b = it >> 6;
        int pos = base[b] + atomicAdd(&cnt[b], 1);
        scv_i[pos] = ((ull)__float_as_uint(v) << 32) |
                     ((ull)(it & 63) << 24) | (unsigned)u;
    }
}

__global__ __launch_bounds__(256) void place_kernel(
    const int* __restrict__ rp, const ull* __restrict__ scv,
    int2* __restrict__ cv, int rows_log2, int nrows)
{
    __shared__ int wp[256];
    int b  = blockIdx.x;
    int u0 = b << rows_log2;
    int u1 = min(u0 + (1 << rows_log2), nrows);
    int nr = u1 - u0;
    if (nr <= 0) return;
    int bbase = rp[u0];
    int cnt   = rp[u1] - bbase;
    if ((int)threadIdx.x < nr) wp[threadIdx.x] = rp[u0 + threadIdx.x] - bbase;
    __syncthreads();
    for (int k = threadIdx.x; k < cnt; k += blockDim.x) {
        ull w = scv[bbase + k];
        int r = (int)((w >> 24) & 255);
        int dst = atomicAdd(&wp[r], 1);
        cv[bbase + dst] = make_int2((int)(w & 0xFFFFFF), (int)(w >> 32));
    }
}

// Fallback: direct random scatter.
__global__ void scatter_kernel(const int* __restrict__ eu, const int* __restrict__ ei,
                               const float* __restrict__ uiv, const float* __restrict__ iuv,
                               int* __restrict__ wpu, int* __restrict__ wpi,
                               ull* __restrict__ cv_u, ull* __restrict__ cv_i, int E)
{
    int e = blockIdx.x * blockDim.x + threadIdx.x;
    if (e >= E) return;
    int u = eu[e], i = ei[e];
    ull pu = ((ull)__float_as_uint(uiv[e]) << 32) | (unsigned)i;
    ull pi = ((ull)__float_as_uint(iuv[e]) << 32) | (unsigned)u;
    int su = atomicAdd(&wpu[u], 1);
    cv_u[su] = pu;
    int si = atomicAdd(&wpi[i], 1);
    cv_i[si] = pi;
}

// ---------------- f32 -> bf16 conversion ----------------
__global__ void conv_bf16_kernel(const float4* __restrict__ src,
                                 ushort4* __restrict__ dst, int n4)
{
    int i = blockIdx.x * blockDim.x + threadIdx.x;
    if (i >= n4) return;
    float4 v = src[i];
    ushort4 o;
    o.x = f2bf(v.x); o.y = f2bf(v.y); o.z = f2bf(v.z); o.w = f2bf(v.w);
    dst[i] = o;
}

// ---------------- gather SpMM (one wave per row) ----------------

template <int STAGE, int BF16>
__global__ __launch_bounds__(256) void gather_stage(
    const int* __restrict__ rp_u, const int2* __restrict__ cv_u,
    const int* __restrict__ rp_i, const int2* __restrict__ cv_i,
    const float* __restrict__ emb_u, const float* __restrict__ emb_i,
    const ushort* __restrict__ e16_u, const ushort* __restrict__ e16_i,
    ushort* __restrict__ g16_u, ushort* __restrict__ g16_i,
    float* __restrict__ out_u, float* __restrict__ out_i,
    int U, int I)
{
    int wid = (blockIdx.x * blockDim.x + threadIdx.x) >> 6;
    int f   = threadIdx.x & 63;
    if (wid >= U + I) return;

    const int* rp; const int2* cv; float* outp; const float* embp;
    const ushort* src16 = nullptr; const float* srcf = nullptr; int ss = 0;
    ushort* g16p; int row;
    if (wid < U) {
        row = wid; rp = rp_u; cv = cv_u; outp = out_u; embp = emb_u; g16p = g16_u;
        if (BF16) src16 = (STAGE == 1) ? e16_i : g16_i;
        else { srcf = (STAGE == 1) ? emb_i : out_i + 64; ss = (STAGE == 1) ? 64 : 192; }
    } else {
        row = wid - U; rp = rp_i; cv = cv_i; outp = out_i; embp = emb_i; g16p = g16_i;
        if (BF16) src16 = (STAGE == 1) ? e16_u : g16_u;
        else { srcf = (STAGE == 1) ? emb_u : out_u + 64; ss = (STAGE == 1) ? 64 : 192; }
    }

    auto ld = [&](int c) -> float {
        if (BF16) return __uint_as_float((unsigned)src16[c * 64 + f] << 16);
        else      return srcf[c * ss + f];
    };

    int beg = rp[row], end = rp[row + 1];
    float a0 = 0.f, a1 = 0.f, a2 = 0.f, a3 = 0.f;
    int e = beg;
    for (; e + 3 < end; e += 4) {
        int2 c0 = cv[e], c1 = cv[e + 1], c2 = cv[e + 2], c3 = cv[e + 3];
        a0 += __int_as_float(c0.y) * ld(c0.x);
        a1 += __int_as_float(c1.y) * ld(c1.x);
        a2 += __int_as_float(c2.y) * ld(c2.x);
        a3 += __int_as_float(c3.y) * ld(c3.x);
    }
    for (; e < end; ++e) {
        int2 c = cv[e];
        a0 += __int_as_float(c.y) * ld(c.x);
    }
    float acc = (a0 + a1) + (a2 + a3);
    float res = (STAGE == 1) ? embp[row * 64 + f] : outp[row * 192 + 64 + f];
    acc += res;
    outp[row * 192 + (STAGE == 1 ? 64 : 128) + f] = acc;
    if (STAGE == 1) {
        outp[row * 192 + f] = res;                 // emb copy to col 0
        if (BF16) g16p[row * 64 + f] = f2bf(acc);  // bf16 gcn1 for stage 2
    }
}

extern "C" void kernel_launch(void* const* d_in, const int* in_sizes, int n_in,
                              void* d_out, int out_size, void* d_ws, size_t ws_size,
                              hipStream_t stream)
{
    const float* emb_u   = (const float*)d_in[0];
    const float* emb_i   = (const float*)d_in[1];
    const float* ui_vals = (const float*)d_in[2];
    const float* iu_vals = (const float*)d_in[3];
    const int*   e_user  = (const int*)d_in[4];
    const int*   e_item  = (const int*)d_in[5];

    const int F = 64;
    const int U = in_sizes[0] / F;
    const int I = in_sizes[1] / F;
    const int E = in_sizes[4];

    float* out_u = (float*)d_out;            // [U][192]
    float* out_i = out_u + (size_t)U * 192;  // [I][192]

    const int BLK = 256;
    const int LOG_RU = 7, LOG_RI = 6;        // 128 users / 64 items per bucket
    int nb_u = (U + (1 << LOG_RU) - 1) >> LOG_RU;
    int nb_i = (I + (1 << LOG_RI) - 1) >> LOG_RI;

    // ---- workspace bump allocator ----
    char* base = (char*)d_ws;
    size_t off = 0;
    auto alloc = [&](size_t bytes, size_t align) -> char* {
        off = (off + align - 1) & ~(align - 1);
        char* p = base + off;
        off += bytes;
        return p;
    };
    int* deg_u  = (int*)alloc((size_t)U * 4, 4);         // also fallback wp
    int* deg_i  = (int*)alloc((size_t)I * 4, 4);
    int* rp_u   = (int*)alloc((size_t)(U + 1) * 4, 4);
    int* rp_i   = (int*)alloc((size_t)(I + 1) * 4, 4);
    int* bsum   = (int*)alloc(1024 * 4, 4);
    int* bscan  = (int*)alloc(1024 * 4, 4);
    int* gwp_u  = (int*)alloc((size_t)nb_u * 4, 64);
    int* gwp_i  = (int*)alloc((size_t)nb_i * 4, 64);
    ull* cv_u   = (ull*)alloc((size_t)E * 8, 8);
    ull* cv_i   = (ull*)alloc((size_t)E * 8, 8);
    size_t need_small = off;                              // fallback tier
    ull* scv_u  = (ull*)alloc((size_t)E * 8, 8);
    ull* scv_i  = (ull*)alloc((size_t)E * 8, 8);
    size_t need_f32 = off;                                // round-5 tier
    // bf16 gcn1 arrays (persist through stage 2)
    ushort* g16_u = (ushort*)alloc((size_t)U * 64 * 2, 8);
    ushort* g16_i = (ushort*)alloc((size_t)I * 64 * 2, 8);
    size_t need_bf16 = off;
    // emb16 overlays dead scv region (conversion runs after place):
    ushort* e16_u = (ushort*)scv_u;
    ushort* e16_i = e16_u + (size_t)U * 64;
    bool e16_fits = ((size_t)(U + I) * 64 * 2) <= (size_t)2 * E * 8;

    bool full = ws_size >= need_f32 && nb_u <= 1024 && nb_i <= 1024;
    bool bf16 = full && e16_fits && ws_size >= need_bf16;
    if (ws_size < need_small) return;  // not expected on this harness

    // ---- degree count + row pointers ----
    hipMemsetAsync(deg_u, 0, ((size_t)U + I) * 4, stream);
    count_kernel<<<(E + BLK - 1) / BLK, BLK, 0, stream>>>(e_user, e_item, deg_u, deg_i, E);

    int sb_u = (U + 1023) / 1024, sb_i = (I + 1023) / 1024;
    scan_block_kernel<<<sb_u, 1024, 0, stream>>>(deg_u, U, rp_u, bsum);
    scan_block_kernel<<<1, 1024, 0, stream>>>(bsum, sb_u, bscan, nullptr);
    scan_fixup_kernel<<<(U + 1 + BLK - 1) / BLK, BLK, 0, stream>>>(
        rp_u, full ? nullptr : deg_u, bscan, U, E);
    scan_block_kernel<<<sb_i, 1024, 0, stream>>>(deg_i, I, rp_i, bsum);
    scan_block_kernel<<<1, 1024, 0, stream>>>(bsum, sb_i, bscan, nullptr);
    scan_fixup_kernel<<<(I + 1 + BLK - 1) / BLK, BLK, 0, stream>>>(
        rp_i, full ? nullptr : deg_i, bscan, I, E);

    if (full) {
        int nbmax = max(nb_u, nb_i);
        bwp_init_kernel<<<(nbmax + BLK - 1) / BLK, BLK, 0, stream>>>(
            rp_u, rp_i, gwp_u, gwp_i, nb_u, nb_i, U, I);
        int ntiles = (E + TILE - 1) / TILE;
        bin2_kernel<<<ntiles, BLK, 0, stream>>>(
            e_user, e_item, ui_vals, iu_vals, gwp_u, gwp_i,
            scv_u, scv_i, E, nb_u, nb_i);
        place_kernel<<<nb_u, BLK, 0, stream>>>(rp_u, scv_u, (int2*)cv_u, LOG_RU, U);
        place_kernel<<<nb_i, BLK, 0, stream>>>(rp_i, scv_i, (int2*)cv_i, LOG_RI, I);
    } else {
        scatter_kernel<<<(E + BLK - 1) / BLK, BLK, 0, stream>>>(
            e_user, e_item, ui_vals, iu_vals, deg_u, deg_i, cv_u, cv_i, E);
    }

    int grid_g = ((U + I) * 64 + BLK - 1) / BLK;
    if (bf16) {
        // emb -> bf16 (into dead scv region)
        conv_bf16_kernel<<<(U * 16 + BLK - 1) / BLK, BLK, 0, stream>>>(
            (const float4*)emb_u, (ushort4*)e16_u, U * 16);
        conv_bf16_kernel<<<(I * 16 + BLK - 1) / BLK, BLK, 0, stream>>>(
            (const float4*)emb_i, (ushort4*)e16_i, I * 16);
        gather_stage<1, 1><<<grid_g, BLK, 0, stream>>>(
            rp_u, (const int2*)cv_u, rp_i, (const int2*)cv_i,
            emb_u, emb_i, e16_u, e16_i, g16_u, g16_i, out_u, out_i, U, I);
        gather_stage<2, 1><<<grid_g, BLK, 0, stream>>>(
            rp_u, (const int2*)cv_u, rp_i, (const int2*)cv_i,
            emb_u, emb_i, e16_u, e16_i, g16_u, g16_i, out_u, out_i, U, I);
    } else {
        gather_stage<1, 0><<<grid_g, BLK, 0, stream>>>(
            rp_u, (const int2*)cv_u, rp_i, (const int2*)cv_i,
            emb_u, emb_i, nullptr, nullptr, nullptr, nullptr, out_u, out_i, U, I);
        gather_stage<2, 0><<<grid_g, BLK, 0, stream>>>(
            rp_u, (const int2*)cv_u, rp_i, (const int2*)cv_i,
            emb_u, emb_i, nullptr, nullptr, nullptr, nullptr, out_u, out_i, U, I);
    }
}

// Round 8
// 496.230 us; speedup vs baseline: 4.9611x; 1.0400x over previous
//
#include <hip/hip_runtime.h>

// d_out layout: gcn_users [U][192] then gcn_items [I][192]
//   cols 0:64 = emb, 64:128 = gcn1, 128:192 = gcn2
//
// Pipeline (8 dispatches):
//   memset(bcnt) -> hist (bucket counts) -> scan (1 WG, bucket bases) ->
//   bin (tiled reservation, scv[2E] = ((row<<24)|col, val)) ->
//   place (per-bucket: LDS row-count + scan -> rp_u/rp_i + cv[2E]) ->
//   conv emb->bf16 (x2, overlay dead scv) -> gather<1> -> gather<2>.
// Buckets: user rows 128/bucket (b = u>>7), item rows 64/bucket; combined
// bucket space [0, nb_u + nb_i); cv/scv/rp offsets are absolute.

typedef unsigned long long ull;

#define TILE   8192
#define MAX_NB 2048

__device__ inline ushort f2bf(float x) {            // RNE f32 -> bf16
    unsigned u = __float_as_uint(x);
    return (ushort)((u + 0x7FFF + ((u >> 16) & 1)) >> 16);
}

// ---------------- 1. bucket histogram ----------------
__global__ __launch_bounds__(256) void hist_kernel(
    const int* __restrict__ eu, const int* __restrict__ ei,
    int* __restrict__ bcnt, int E, int nb_u, int nb)
{
    __shared__ int cnt[MAX_NB];
    int t0 = blockIdx.x * TILE;
    int n  = min(TILE, E - t0);
    for (int b = threadIdx.x; b < nb; b += 256) cnt[b] = 0;
    __syncthreads();
    for (int k = threadIdx.x; k < n; k += 256) {
        atomicAdd(&cnt[eu[t0 + k] >> 7], 1);
        atomicAdd(&cnt[nb_u + (ei[t0 + k] >> 6)], 1);
    }
    __syncthreads();
    for (int b = threadIdx.x; b < nb; b += 256)
        if (cnt[b]) atomicAdd(&bcnt[b], cnt[b]);
}

// ---------------- 2. single-WG exclusive scan (nb <= 4096) ----------------
__global__ __launch_bounds__(1024) void scan_kernel(
    const int* __restrict__ bcnt, int* __restrict__ rp_b, int* __restrict__ gwp, int nb)
{
    __shared__ int part[1024];
    int t  = threadIdx.x;
    int i0 = t * 4;
    int x0 = (i0 + 0 < nb) ? bcnt[i0 + 0] : 0;
    int x1 = (i0 + 1 < nb) ? bcnt[i0 + 1] : 0;
    int x2 = (i0 + 2 < nb) ? bcnt[i0 + 2] : 0;
    int x3 = (i0 + 3 < nb) ? bcnt[i0 + 3] : 0;
    int s = x0 + x1 + x2 + x3;
    part[t] = s;
    __syncthreads();
    #pragma unroll
    for (int off = 1; off < 1024; off <<= 1) {
        int v = (t >= off) ? part[t - off] : 0;
        __syncthreads();
        part[t] += v;
        __syncthreads();
    }
    int p = part[t] - s;
    if (i0 + 0 < nb) { rp_b[i0 + 0] = p; gwp[i0 + 0] = p; p += x0; }
    if (i0 + 1 < nb) { rp_b[i0 + 1] = p; gwp[i0 + 1] = p; p += x1; }
    if (i0 + 2 < nb) { rp_b[i0 + 2] = p; gwp[i0 + 2] = p; p += x2; }
    if (i0 + 3 < nb) { rp_b[i0 + 3] = p; gwp[i0 + 3] = p; p += x3; }
    if (t == 1023) rp_b[nb] = part[1023];
}

// ---------------- 3. tiled reservation binning (both sides) ----------------
__global__ __launch_bounds__(256) void bin_kernel(
    const int* __restrict__ eu, const int* __restrict__ ei,
    const float* __restrict__ uiv, const float* __restrict__ iuv,
    int* __restrict__ gwp, int2* __restrict__ scv,
    int E, int nb_u, int nb)
{
    __shared__ int cnt[MAX_NB];
    __shared__ int base[MAX_NB];
    int t0 = blockIdx.x * TILE;
    int n  = min(TILE, E - t0);
    for (int b = threadIdx.x; b < nb; b += 256) cnt[b] = 0;
    __syncthreads();
    for (int k = threadIdx.x; k < n; k += 256) {
        atomicAdd(&cnt[eu[t0 + k] >> 7], 1);
        atomicAdd(&cnt[nb_u + (ei[t0 + k] >> 6)], 1);
    }
    __syncthreads();
    for (int b = threadIdx.x; b < nb; b += 256) {
        int c = cnt[b];
        base[b] = c ? atomicAdd(&gwp[b], c) : 0;
        cnt[b] = 0;
    }
    __syncthreads();
    for (int k = threadIdx.x; k < n; k += 256) {
        int u = eu[t0 + k], it = ei[t0 + k];
        int bu = u >> 7;
        int pu = base[bu] + atomicAdd(&cnt[bu], 1);
        scv[pu] = make_int2(((u & 127) << 24) | it, __float_as_int(uiv[t0 + k]));
        int bi = nb_u + (it >> 6);
        int pi = base[bi] + atomicAdd(&cnt[bi], 1);
        scv[pi] = make_int2(((it & 63) << 24) | u, __float_as_int(iuv[t0 + k]));
    }
}

// ---------------- 4. per-bucket place: row offsets + ordered cv ----------------
__global__ __launch_bounds__(256) void place_kernel(
    const int* __restrict__ rp_b, const int2* __restrict__ scv,
    int2* __restrict__ cv, int* __restrict__ rp_u, int* __restrict__ rp_i,
    int nb_u, int U, int I)
{
    __shared__ int cnt[128];
    __shared__ int wp[128];
    int b = blockIdx.x;
    bool uside = (b < nb_u);
    int rl2   = uside ? 7 : 6;
    int row0  = (uside ? b : b - nb_u) << rl2;
    int ntot  = uside ? U : I;
    int nr    = min(1 << rl2, ntot - row0);
    int* rpo  = uside ? rp_u : rp_i;
    int bbase = rp_b[b], bend = rp_b[b + 1];
    int t = threadIdx.x;

    if (t < 128) cnt[t] = 0;
    __syncthreads();
    for (int k = bbase + t; k < bend; k += 256)
        atomicAdd(&cnt[(unsigned)scv[k].x >> 24], 1);
    __syncthreads();

    // exclusive scan of cnt[0..127] into wp
    int x = (t < 128) ? cnt[t] : 0;
    if (t < 128) wp[t] = x;
    __syncthreads();
    #pragma unroll
    for (int o = 1; o < 128; o <<= 1) {
        int v = (t < 128 && t >= o) ? wp[t - o] : 0;
        __syncthreads();
        if (t < 128) wp[t] += v;
        __syncthreads();
    }
    int excl = (t < 128) ? wp[t] - x : 0;
    if (t < 128) wp[t] = excl;
    if (t < nr) rpo[row0 + t] = bbase + excl;
    if (t == 0 && row0 + nr == ntot) rpo[ntot] = bend;
    __syncthreads();

    for (int k = bbase + t; k < bend; k += 256) {
        int2 w = scv[k];
        int r = (unsigned)w.x >> 24;
        int dst = bbase + atomicAdd(&wp[r], 1);
        cv[dst] = make_int2(w.x & 0xFFFFFF, w.y);
    }
}

// ---------------- f32 -> bf16 conversion ----------------
__global__ void conv_bf16_kernel(const float4* __restrict__ src,
                                 ushort4* __restrict__ dst, int n4)
{
    int i = blockIdx.x * blockDim.x + threadIdx.x;
    if (i >= n4) return;
    float4 v = src[i];
    ushort4 o;
    o.x = f2bf(v.x); o.y = f2bf(v.y); o.z = f2bf(v.z); o.w = f2bf(v.w);
    dst[i] = o;
}

// ---------------- gather SpMM (one wave per row, bf16 sources) ----------------
template <int STAGE>
__global__ __launch_bounds__(256) void gather_stage(
    const int* __restrict__ rp_u, const int* __restrict__ rp_i,
    const ull* __restrict__ cv,
    const float* __restrict__ emb_u, const float* __restrict__ emb_i,
    const ushort* __restrict__ e16_u, const ushort* __restrict__ e16_i,
    ushort* __restrict__ g16_u, ushort* __restrict__ g16_i,
    float* __restrict__ out_u, float* __restrict__ out_i,
    int U, int I)
{
    int wid = (blockIdx.x * blockDim.x + threadIdx.x) >> 6;
    int f   = threadIdx.x & 63;
    if (wid >= U + I) return;

    const int* rp; float* outp; const float* embp;
    const ushort* src16; ushort* g16p; int row;
    if (wid < U) {
        row = wid; rp = rp_u; outp = out_u; embp = emb_u; g16p = g16_u;
        src16 = (STAGE == 1) ? e16_i : g16_i;
    } else {
        row = wid - U; rp = rp_i; outp = out_i; embp = emb_i; g16p = g16_i;
        src16 = (STAGE == 1) ? e16_u : g16_u;
    }

    int beg = rp[row], end = rp[row + 1];
    float a0 = 0.f, a1 = 0.f, a2 = 0.f, a3 = 0.f;
    int e = beg;
    for (; e + 3 < end; e += 4) {
        ull w0 = __builtin_nontemporal_load(&cv[e]);
        ull w1 = __builtin_nontemporal_load(&cv[e + 1]);
        ull w2 = __builtin_nontemporal_load(&cv[e + 2]);
        ull w3 = __builtin_nontemporal_load(&cv[e + 3]);
        a0 += __uint_as_float((unsigned)(w0 >> 32)) *
              __uint_as_float((unsigned)src16[(unsigned)(w0 & 0xFFFFFF) * 64 + f] << 16);
        a1 += __uint_as_float((unsigned)(w1 >> 32)) *
              __uint_as_float((unsigned)src16[(unsigned)(w1 & 0xFFFFFF) * 64 + f] << 16);
        a2 += __uint_as_float((unsigned)(w2 >> 32)) *
              __uint_as_float((unsigned)src16[(unsigned)(w2 & 0xFFFFFF) * 64 + f] << 16);
        a3 += __uint_as_float((unsigned)(w3 >> 32)) *
              __uint_as_float((unsigned)src16[(unsigned)(w3 & 0xFFFFFF) * 64 + f] << 16);
    }
    for (; e < end; ++e) {
        ull w = __builtin_nontemporal_load(&cv[e]);
        a0 += __uint_as_float((unsigned)(w >> 32)) *
              __uint_as_float((unsigned)src16[(unsigned)(w & 0xFFFFFF) * 64 + f] << 16);
    }
    float acc = (a0 + a1) + (a2 + a3);
    float res = (STAGE == 1) ? embp[row * 64 + f] : outp[row * 192 + 64 + f];
    acc += res;
    outp[row * 192 + (STAGE == 1 ? 64 : 128) + f] = acc;
    if (STAGE == 1) {
        outp[row * 192 + f] = res;          // emb copy to col 0
        g16p[row * 64 + f] = f2bf(acc);     // bf16 gcn1 for stage 2
    }
}

// ---------------- fallback (ws-free atomic path) ----------------
__global__ void init_dup_kernel(const float4* __restrict__ src,
                                float4* __restrict__ dst, int nrows)
{
    int gid = blockIdx.x * blockDim.x + threadIdx.x;
    if (gid >= nrows * 16) return;
    int row = gid >> 4, c = gid & 15;
    float4 v = src[gid];
    dst[row * 48 + c]      = v;
    dst[row * 48 + 16 + c] = v;
}
__global__ void copy_col_kernel(float4* __restrict__ buf, int nrows)
{
    int gid = blockIdx.x * blockDim.x + threadIdx.x;
    if (gid >= nrows * 16) return;
    int row = gid >> 4, c = gid & 15;
    buf[row * 48 + 32 + c] = buf[row * 48 + 16 + c];
}
__global__ void spmm_atomic(const int* __restrict__ eu, const int* __restrict__ ei,
                            const float* __restrict__ uiv, const float* __restrict__ iuv,
                            const float* __restrict__ su, int ssu,
                            const float* __restrict__ si, int ssi,
                            float* __restrict__ ou, float* __restrict__ oi,
                            int dst_col, int E)
{
    int gid = blockIdx.x * blockDim.x + threadIdx.x;
    if (gid >= E * 64) return;
    int e = gid >> 6, f = gid & 63;
    int u = eu[e], i = ei[e];
    unsafeAtomicAdd(&ou[u * 192 + dst_col + f], uiv[e] * si[i * ssi + f]);
    unsafeAtomicAdd(&oi[i * 192 + dst_col + f], iuv[e] * su[u * ssu + f]);
}

extern "C" void kernel_launch(void* const* d_in, const int* in_sizes, int n_in,
                              void* d_out, int out_size, void* d_ws, size_t ws_size,
                              hipStream_t stream)
{
    const float* emb_u   = (const float*)d_in[0];
    const float* emb_i   = (const float*)d_in[1];
    const float* ui_vals = (const float*)d_in[2];
    const float* iu_vals = (const float*)d_in[3];
    const int*   e_user  = (const int*)d_in[4];
    const int*   e_item  = (const int*)d_in[5];

    const int F = 64;
    const int U = in_sizes[0] / F;
    const int I = in_sizes[1] / F;
    const int E = in_sizes[4];

    float* out_u = (float*)d_out;            // [U][192]
    float* out_i = out_u + (size_t)U * 192;  // [I][192]

    const int BLK = 256;
    int nb_u = (U + 127) >> 7;
    int nb_i = (I + 63) >> 6;
    int nb   = nb_u + nb_i;

    // ---- workspace bump allocator ----
    char* base = (char*)d_ws;
    size_t off = 0;
    auto alloc = [&](size_t bytes, size_t align) -> char* {
        off = (off + align - 1) & ~(align - 1);
        char* p = base + off;
        off += bytes;
        return p;
    };
    int*  bcnt = (int*)alloc((size_t)nb * 4, 4);
    int*  rp_b = (int*)alloc((size_t)(nb + 1) * 4, 4);
    int*  gwp  = (int*)alloc((size_t)nb * 4, 4);
    int*  rp_u = (int*)alloc((size_t)(U + 1) * 4, 4);
    int*  rp_i = (int*)alloc((size_t)(I + 1) * 4, 4);
    int2* cv   = (int2*)alloc((size_t)2 * E * 8, 8);
    int2* scv  = (int2*)alloc((size_t)2 * E * 8, 8);
    ushort* g16_u = (ushort*)alloc((size_t)U * 64 * 2, 8);
    ushort* g16_i = (ushort*)alloc((size_t)I * 64 * 2, 8);
    size_t need = off;
    // emb16 overlays dead scv (conversion runs after place)
    ushort* e16_u = (ushort*)scv;
    ushort* e16_i = e16_u + (size_t)U * 64;
    bool e16_fits = ((size_t)(U + I) * 64 * 2) <= (size_t)2 * E * 8;

    if (ws_size < need || nb > MAX_NB || !e16_fits) {
        // fallback: ws-free atomic path
        int grid_u = (U * 16 + BLK - 1) / BLK;
        int grid_i = (I * 16 + BLK - 1) / BLK;
        long long tt = (long long)E * 64;
        int grid_e = (int)((tt + BLK - 1) / BLK);
        init_dup_kernel<<<grid_u, BLK, 0, stream>>>((const float4*)emb_u, (float4*)out_u, U);
        init_dup_kernel<<<grid_i, BLK, 0, stream>>>((const float4*)emb_i, (float4*)out_i, I);
        spmm_atomic<<<grid_e, BLK, 0, stream>>>(e_user, e_item, ui_vals, iu_vals,
                                                emb_u, 64, emb_i, 64, out_u, out_i, 64, E);
        copy_col_kernel<<<grid_u, BLK, 0, stream>>>((float4*)out_u, U);
        copy_col_kernel<<<grid_i, BLK, 0, stream>>>((float4*)out_i, I);
        spmm_atomic<<<grid_e, BLK, 0, stream>>>(e_user, e_item, ui_vals, iu_vals,
                                                out_u + 64, 192, out_i + 64, 192,
                                                out_u, out_i, 128, E);
        return;
    }

    int ntiles = (E + TILE - 1) / TILE;

    hipMemsetAsync(bcnt, 0, (size_t)nb * 4, stream);
    hist_kernel<<<ntiles, BLK, 0, stream>>>(e_user, e_item, bcnt, E, nb_u, nb);
    scan_kernel<<<1, 1024, 0, stream>>>(bcnt, rp_b, gwp, nb);
    bin_kernel<<<ntiles, BLK, 0, stream>>>(e_user, e_item, ui_vals, iu_vals,
                                           gwp, scv, E, nb_u, nb);
    place_kernel<<<nb, BLK, 0, stream>>>(rp_b, scv, cv, rp_u, rp_i, nb_u, U, I);

    conv_bf16_kernel<<<(U * 16 + BLK - 1) / BLK, BLK, 0, stream>>>(
        (const float4*)emb_u, (ushort4*)e16_u, U * 16);
    conv_bf16_kernel<<<(I * 16 + BLK - 1) / BLK, BLK, 0, stream>>>(
        (const float4*)emb_i, (ushort4*)e16_i, I * 16);

    int grid_g = ((U + I) * 64 + BLK - 1) / BLK;
    gather_stage<1><<<grid_g, BLK, 0, stream>>>(
        rp_u, rp_i, (const ull*)cv, emb_u, emb_i, e16_u, e16_i,
        g16_u, g16_i, out_u, out_i, U, I);
    gather_stage<2><<<grid_g, BLK, 0, stream>>>(
        rp_u, rp_i, (const ull*)cv, emb_u, emb_i, e16_u, e16_i,
        g16_u, g16_i, out_u, out_i, U, I);
}

// Round 9
// 410.580 us; speedup vs baseline: 5.9960x; 1.2086x over previous
//
#include <hip/hip_runtime.h>

// d_out layout: gcn_users [U][192] then gcn_items [I][192]
//   cols 0:64 = emb, 64:128 = gcn1, 128:192 = gcn2
//
// Pipeline (8 dispatches):
//   memset(bcnt) -> hist (bucket counts) -> scan (1 WG, bucket bases) ->
//   bin (tiled reservation, scv[2E] = ((row<<24)|col, val)) ->
//   place (per-bucket: LDS row-count + scan -> rp_u/rp_i + cv[2E]) ->
//   conv emb->bf16 (x2, overlay dead scv) -> gather<1> -> gather<2>.
// Gather: one wave per row, bf16 sources, PLAIN cached loads for cv
// (round-8 nontemporal-load experiment regressed: cv lines are re-touched
// across iterations; NT evicts them early -> +33MB FETCH, +40us/dispatch).

typedef unsigned long long ull;

#define TILE   8192
#define MAX_NB 2048

__device__ inline ushort f2bf(float x) {            // RNE f32 -> bf16
    unsigned u = __float_as_uint(x);
    return (ushort)((u + 0x7FFF + ((u >> 16) & 1)) >> 16);
}

// ---------------- 1. bucket histogram ----------------
__global__ __launch_bounds__(256) void hist_kernel(
    const int* __restrict__ eu, const int* __restrict__ ei,
    int* __restrict__ bcnt, int E, int nb_u, int nb)
{
    __shared__ int cnt[MAX_NB];
    int t0 = blockIdx.x * TILE;
    int n  = min(TILE, E - t0);
    for (int b = threadIdx.x; b < nb; b += 256) cnt[b] = 0;
    __syncthreads();
    for (int k = threadIdx.x; k < n; k += 256) {
        atomicAdd(&cnt[eu[t0 + k] >> 7], 1);
        atomicAdd(&cnt[nb_u + (ei[t0 + k] >> 6)], 1);
    }
    __syncthreads();
    for (int b = threadIdx.x; b < nb; b += 256)
        if (cnt[b]) atomicAdd(&bcnt[b], cnt[b]);
}

// ---------------- 2. single-WG exclusive scan (nb <= 4096) ----------------
__global__ __launch_bounds__(1024) void scan_kernel(
    const int* __restrict__ bcnt, int* __restrict__ rp_b, int* __restrict__ gwp, int nb)
{
    __shared__ int part[1024];
    int t  = threadIdx.x;
    int i0 = t * 4;
    int x0 = (i0 + 0 < nb) ? bcnt[i0 + 0] : 0;
    int x1 = (i0 + 1 < nb) ? bcnt[i0 + 1] : 0;
    int x2 = (i0 + 2 < nb) ? bcnt[i0 + 2] : 0;
    int x3 = (i0 + 3 < nb) ? bcnt[i0 + 3] : 0;
    int s = x0 + x1 + x2 + x3;
    part[t] = s;
    __syncthreads();
    #pragma unroll
    for (int off = 1; off < 1024; off <<= 1) {
        int v = (t >= off) ? part[t - off] : 0;
        __syncthreads();
        part[t] += v;
        __syncthreads();
    }
    int p = part[t] - s;
    if (i0 + 0 < nb) { rp_b[i0 + 0] = p; gwp[i0 + 0] = p; p += x0; }
    if (i0 + 1 < nb) { rp_b[i0 + 1] = p; gwp[i0 + 1] = p; p += x1; }
    if (i0 + 2 < nb) { rp_b[i0 + 2] = p; gwp[i0 + 2] = p; p += x2; }
    if (i0 + 3 < nb) { rp_b[i0 + 3] = p; gwp[i0 + 3] = p; p += x3; }
    if (t == 1023) rp_b[nb] = part[1023];
}

// ---------------- 3. tiled reservation binning (both sides) ----------------
__global__ __launch_bounds__(256) void bin_kernel(
    const int* __restrict__ eu, const int* __restrict__ ei,
    const float* __restrict__ uiv, const float* __restrict__ iuv,
    int* __restrict__ gwp, int2* __restrict__ scv,
    int E, int nb_u, int nb)
{
    __shared__ int cnt[MAX_NB];
    __shared__ int base[MAX_NB];
    int t0 = blockIdx.x * TILE;
    int n  = min(TILE, E - t0);
    for (int b = threadIdx.x; b < nb; b += 256) cnt[b] = 0;
    __syncthreads();
    for (int k = threadIdx.x; k < n; k += 256) {
        atomicAdd(&cnt[eu[t0 + k] >> 7], 1);
        atomicAdd(&cnt[nb_u + (ei[t0 + k] >> 6)], 1);
    }
    __syncthreads();
    for (int b = threadIdx.x; b < nb; b += 256) {
        int c = cnt[b];
        base[b] = c ? atomicAdd(&gwp[b], c) : 0;
        cnt[b] = 0;
    }
    __syncthreads();
    for (int k = threadIdx.x; k < n; k += 256) {
        int u = eu[t0 + k], it = ei[t0 + k];
        int bu = u >> 7;
        int pu = base[bu] + atomicAdd(&cnt[bu], 1);
        scv[pu] = make_int2(((u & 127) << 24) | it, __float_as_int(uiv[t0 + k]));
        int bi = nb_u + (it >> 6);
        int pi = base[bi] + atomicAdd(&cnt[bi], 1);
        scv[pi] = make_int2(((it & 63) << 24) | u, __float_as_int(iuv[t0 + k]));
    }
}

// ---------------- 4. per-bucket place: row offsets + ordered cv ----------------
__global__ __launch_bounds__(256) void place_kernel(
    const int* __restrict__ rp_b, const int2* __restrict__ scv,
    int2* __restrict__ cv, int* __restrict__ rp_u, int* __restrict__ rp_i,
    int nb_u, int U, int I)
{
    __shared__ int cnt[128];
    __shared__ int wp[128];
    int b = blockIdx.x;
    bool uside = (b < nb_u);
    int rl2   = uside ? 7 : 6;
    int row0  = (uside ? b : b - nb_u) << rl2;
    int ntot  = uside ? U : I;
    int nr    = min(1 << rl2, ntot - row0);
    int* rpo  = uside ? rp_u : rp_i;
    int bbase = rp_b[b], bend = rp_b[b + 1];
    int t = threadIdx.x;

    if (t < 128) cnt[t] = 0;
    __syncthreads();
    for (int k = bbase + t; k < bend; k += 256)
        atomicAdd(&cnt[(unsigned)scv[k].x >> 24], 1);
    __syncthreads();

    // exclusive scan of cnt[0..127] into wp
    int x = (t < 128) ? cnt[t] : 0;
    if (t < 128) wp[t] = x;
    __syncthreads();
    #pragma unroll
    for (int o = 1; o < 128; o <<= 1) {
        int v = (t < 128 && t >= o) ? wp[t - o] : 0;
        __syncthreads();
        if (t < 128) wp[t] += v;
        __syncthreads();
    }
    int excl = (t < 128) ? wp[t] - x : 0;
    if (t < 128) wp[t] = excl;
    if (t < nr) rpo[row0 + t] = bbase + excl;
    if (t == 0 && row0 + nr == ntot) rpo[ntot] = bend;
    __syncthreads();

    for (int k = bbase + t; k < bend; k += 256) {
        int2 w = scv[k];
        int r = (unsigned)w.x >> 24;
        int dst = bbase + atomicAdd(&wp[r], 1);
        cv[dst] = make_int2(w.x & 0xFFFFFF, w.y);
    }
}

// ---------------- f32 -> bf16 conversion ----------------
__global__ void conv_bf16_kernel(const float4* __restrict__ src,
                                 ushort4* __restrict__ dst, int n4)
{
    int i = blockIdx.x * blockDim.x + threadIdx.x;
    if (i >= n4) return;
    float4 v = src[i];
    ushort4 o;
    o.x = f2bf(v.x); o.y = f2bf(v.y); o.z = f2bf(v.z); o.w = f2bf(v.w);
    dst[i] = o;
}

// ---------------- gather SpMM (one wave per row, bf16 sources) ----------------
template <int STAGE>
__global__ __launch_bounds__(256) void gather_stage(
    const int* __restrict__ rp_u, const int* __restrict__ rp_i,
    const int2* __restrict__ cv,
    const float* __restrict__ emb_u, const float* __restrict__ emb_i,
    const ushort* __restrict__ e16_u, const ushort* __restrict__ e16_i,
    ushort* __restrict__ g16_u, ushort* __restrict__ g16_i,
    float* __restrict__ out_u, float* __restrict__ out_i,
    int U, int I)
{
    int wid = (blockIdx.x * blockDim.x + threadIdx.x) >> 6;
    int f   = threadIdx.x & 63;
    if (wid >= U + I) return;

    const int* rp; float* outp; const float* embp;
    const ushort* src16; ushort* g16p; int row;
    if (wid < U) {
        row = wid; rp = rp_u; outp = out_u; embp = emb_u; g16p = g16_u;
        src16 = (STAGE == 1) ? e16_i : g16_i;
    } else {
        row = wid - U; rp = rp_i; outp = out_i; embp = emb_i; g16p = g16_i;
        src16 = (STAGE == 1) ? e16_u : g16_u;
    }

    int beg = rp[row], end = rp[row + 1];
    float a0 = 0.f, a1 = 0.f, a2 = 0.f, a3 = 0.f;
    int e = beg;
    for (; e + 3 < end; e += 4) {
        int2 c0 = cv[e],     c1 = cv[e + 1];
        int2 c2 = cv[e + 2], c3 = cv[e + 3];
        a0 += __int_as_float(c0.y) *
              __uint_as_float((unsigned)src16[(unsigned)c0.x * 64 + f] << 16);
        a1 += __int_as_float(c1.y) *
              __uint_as_float((unsigned)src16[(unsigned)c1.x * 64 + f] << 16);
        a2 += __int_as_float(c2.y) *
              __uint_as_float((unsigned)src16[(unsigned)c2.x * 64 + f] << 16);
        a3 += __int_as_float(c3.y) *
              __uint_as_float((unsigned)src16[(unsigned)c3.x * 64 + f] << 16);
    }
    for (; e < end; ++e) {
        int2 c = cv[e];
        a0 += __int_as_float(c.y) *
              __uint_as_float((unsigned)src16[(unsigned)c.x * 64 + f] << 16);
    }
    float acc = (a0 + a1) + (a2 + a3);
    float res = (STAGE == 1) ? embp[row * 64 + f] : outp[row * 192 + 64 + f];
    acc += res;
    outp[row * 192 + (STAGE == 1 ? 64 : 128) + f] = acc;
    if (STAGE == 1) {
        outp[row * 192 + f] = res;          // emb copy to col 0
        g16p[row * 64 + f] = f2bf(acc);     // bf16 gcn1 for stage 2
    }
}

// ---------------- fallback (ws-free atomic path) ----------------
__global__ void init_dup_kernel(const float4* __restrict__ src,
                                float4* __restrict__ dst, int nrows)
{
    int gid = blockIdx.x * blockDim.x + threadIdx.x;
    if (gid >= nrows * 16) return;
    int row = gid >> 4, c = gid & 15;
    float4 v = src[gid];
    dst[row * 48 + c]      = v;
    dst[row * 48 + 16 + c] = v;
}
__global__ void copy_col_kernel(float4* __restrict__ buf, int nrows)
{
    int gid = blockIdx.x * blockDim.x + threadIdx.x;
    if (gid >= nrows * 16) return;
    int row = gid >> 4, c = gid & 15;
    buf[row * 48 + 32 + c] = buf[row * 48 + 16 + c];
}
__global__ void spmm_atomic(const int* __restrict__ eu, const int* __restrict__ ei,
                            const float* __restrict__ uiv, const float* __restrict__ iuv,
                            const float* __restrict__ su, int ssu,
                            const float* __restrict__ si, int ssi,
                            float* __restrict__ ou, float* __restrict__ oi,
                            int dst_col, int E)
{
    int gid = blockIdx.x * blockDim.x + threadIdx.x;
    if (gid >= E * 64) return;
    int e = gid >> 6, f = gid & 63;
    int u = eu[e], i = ei[e];
    unsafeAtomicAdd(&ou[u * 192 + dst_col + f], uiv[e] * si[i * ssi + f]);
    unsafeAtomicAdd(&oi[i * 192 + dst_col + f], iuv[e] * su[u * ssu + f]);
}

extern "C" void kernel_launch(void* const* d_in, const int* in_sizes, int n_in,
                              void* d_out, int out_size, void* d_ws, size_t ws_size,
                              hipStream_t stream)
{
    const float* emb_u   = (const float*)d_in[0];
    const float* emb_i   = (const float*)d_in[1];
    const float* ui_vals = (const float*)d_in[2];
    const float* iu_vals = (const float*)d_in[3];
    const int*   e_user  = (const int*)d_in[4];
    const int*   e_item  = (const int*)d_in[5];

    const int F = 64;
    const int U = in_sizes[0] / F;
    const int I = in_sizes[1] / F;
    const int E = in_sizes[4];

    float* out_u = (float*)d_out;            // [U][192]
    float* out_i = out_u + (size_t)U * 192;  // [I][192]

    const int BLK = 256;
    int nb_u = (U + 127) >> 7;
    int nb_i = (I + 63) >> 6;
    int nb   = nb_u + nb_i;

    // ---- workspace bump allocator ----
    char* base = (char*)d_ws;
    size_t off = 0;
    auto alloc = [&](size_t bytes, size_t align) -> char* {
        off = (off + align - 1) & ~(align - 1);
        char* p = base + off;
        off += bytes;
        return p;
    };
    int*  bcnt = (int*)alloc((size_t)nb * 4, 4);
    int*  rp_b = (int*)alloc((size_t)(nb + 1) * 4, 4);
    int*  gwp  = (int*)alloc((size_t)nb * 4, 4);
    int*  rp_u = (int*)alloc((size_t)(U + 1) * 4, 4);
    int*  rp_i = (int*)alloc((size_t)(I + 1) * 4, 4);
    int2* cv   = (int2*)alloc((size_t)2 * E * 8, 8);
    int2* scv  = (int2*)alloc((size_t)2 * E * 8, 8);
    ushort* g16_u = (ushort*)alloc((size_t)U * 64 * 2, 8);
    ushort* g16_i = (ushort*)alloc((size_t)I * 64 * 2, 8);
    size_t need = off;
    // emb16 overlays dead scv (conversion runs after place)
    ushort* e16_u = (ushort*)scv;
    ushort* e16_i = e16_u + (size_t)U * 64;
    bool e16_fits = ((size_t)(U + I) * 64 * 2) <= (size_t)2 * E * 8;

    if (ws_size < need || nb > MAX_NB || !e16_fits) {
        // fallback: ws-free atomic path
        int grid_u = (U * 16 + BLK - 1) / BLK;
        int grid_i = (I * 16 + BLK - 1) / BLK;
        long long tt = (long long)E * 64;
        int grid_e = (int)((tt + BLK - 1) / BLK);
        init_dup_kernel<<<grid_u, BLK, 0, stream>>>((const float4*)emb_u, (float4*)out_u, U);
        init_dup_kernel<<<grid_i, BLK, 0, stream>>>((const float4*)emb_i, (float4*)out_i, I);
        spmm_atomic<<<grid_e, BLK, 0, stream>>>(e_user, e_item, ui_vals, iu_vals,
                                                emb_u, 64, emb_i, 64, out_u, out_i, 64, E);
        copy_col_kernel<<<grid_u, BLK, 0, stream>>>((float4*)out_u, U);
        copy_col_kernel<<<grid_i, BLK, 0, stream>>>((float4*)out_i, I);
        spmm_atomic<<<grid_e, BLK, 0, stream>>>(e_user, e_item, ui_vals, iu_vals,
                                                out_u + 64, 192, out_i + 64, 192,
                                                out_u, out_i, 128, E);
        return;
    }

    int ntiles = (E + TILE - 1) / TILE;

    hipMemsetAsync(bcnt, 0, (size_t)nb * 4, stream);
    hist_kernel<<<ntiles, BLK, 0, stream>>>(e_user, e_item, bcnt, E, nb_u, nb);
    scan_kernel<<<1, 1024, 0, stream>>>(bcnt, rp_b, gwp, nb);
    bin_kernel<<<ntiles, BLK, 0, stream>>>(e_user, e_item, ui_vals, iu_vals,
                                           gwp, scv, E, nb_u, nb);
    place_kernel<<<nb, BLK, 0, stream>>>(rp_b, scv, cv, rp_u, rp_i, nb_u, U, I);

    conv_bf16_kernel<<<(U * 16 + BLK - 1) / BLK, BLK, 0, stream>>>(
        (const float4*)emb_u, (ushort4*)e16_u, U * 16);
    conv_bf16_kernel<<<(I * 16 + BLK - 1) / BLK, BLK, 0, stream>>>(
        (const float4*)emb_i, (ushort4*)e16_i, I * 16);

    int grid_g = ((U + I) * 64 + BLK - 1) / BLK;
    gather_stage<1><<<grid_g, BLK, 0, stream>>>(
        rp_u, rp_i, cv, emb_u, emb_i, e16_u, e16_i,
        g16_u, g16_i, out_u, out_i, U, I);
    gather_stage<2><<<grid_g, BLK, 0, stream>>>(
        rp_u, rp_i, cv, emb_u, emb_i, e16_u, e16_i,
        g16_u, g16_i, out_u, out_i, U, I);
}